// Round 6
// baseline (169.304 us; speedup 1.0000x reference)
//
#include <hip/hip_runtime.h>
#include <math.h>

#define FDIM 256
#define NH 8
#define HD 32
#define NQ 4096
#define NKEY 4096
#define CAP 512
#define HCAP 256   // per-half sub-list capacity (max observed n ~160 total)
#define R2 9.0f

typedef _Float16 half8 __attribute__((ext_vector_type(8)));
typedef float f32x4 __attribute__((ext_vector_type(4)));
typedef unsigned short ushort_t;

// ---------------------------------------------------------------------------
// MFMA GEMM cores: C[m][n] = sum_k A[m][k] * W[n][k]  (K=256). Wave tile
// 16x64, no LDS. f32 operands are converted in-register (single RN rounding,
// numerically identical to a separate cast pass).
// ---------------------------------------------------------------------------
__device__ __forceinline__ void mfma_tile_16x64_f32AW(const float* __restrict__ A,
                                                      const float* __restrict__ W,
                                                      int m0, int n0, int wave, int lane,
                                                      f32x4 acc[4]) {
    const int row  = lane & 15;
    const int quad = lane >> 4;
    const float* aptr = A + (size_t)(m0 + wave * 16 + row) * 256 + quad * 8;
    const float* wptr = W + (size_t)(n0 + row) * 256 + quad * 8;
#pragma unroll
    for (int i = 0; i < 4; ++i) acc[i] = (f32x4){0.f, 0.f, 0.f, 0.f};
#pragma unroll
    for (int k0 = 0; k0 < 8; ++k0) {
        float4 a0 = *(const float4*)(aptr + k0 * 32);
        float4 a1 = *(const float4*)(aptr + k0 * 32 + 4);
        half8 a;
        a[0] = (_Float16)a0.x; a[1] = (_Float16)a0.y;
        a[2] = (_Float16)a0.z; a[3] = (_Float16)a0.w;
        a[4] = (_Float16)a1.x; a[5] = (_Float16)a1.y;
        a[6] = (_Float16)a1.z; a[7] = (_Float16)a1.w;
#pragma unroll
        for (int nt = 0; nt < 4; ++nt) {
            float4 b0 = *(const float4*)(wptr + (size_t)nt * 16 * 256 + k0 * 32);
            float4 b1 = *(const float4*)(wptr + (size_t)nt * 16 * 256 + k0 * 32 + 4);
            half8 b;
            b[0] = (_Float16)b0.x; b[1] = (_Float16)b0.y;
            b[2] = (_Float16)b0.z; b[3] = (_Float16)b0.w;
            b[4] = (_Float16)b1.x; b[5] = (_Float16)b1.y;
            b[6] = (_Float16)b1.z; b[7] = (_Float16)b1.w;
            acc[nt] = __builtin_amdgcn_mfma_f32_16x16x32_f16(a, b, acc[nt], 0, 0, 0);
        }
    }
}

__device__ __forceinline__ void mfma_tile_16x64_f16A_f32W(const _Float16* __restrict__ A,
                                                          const float* __restrict__ W,
                                                          int m0, int n0, int wave, int lane,
                                                          f32x4 acc[4]) {
    const int row  = lane & 15;
    const int quad = lane >> 4;
    const _Float16* aptr = A + (size_t)(m0 + wave * 16 + row) * 256 + quad * 8;
    const float* wptr = W + (size_t)(n0 + row) * 256 + quad * 8;
#pragma unroll
    for (int i = 0; i < 4; ++i) acc[i] = (f32x4){0.f, 0.f, 0.f, 0.f};
#pragma unroll
    for (int k0 = 0; k0 < 8; ++k0) {
        half8 a = *(const half8*)(aptr + k0 * 32);
#pragma unroll
        for (int nt = 0; nt < 4; ++nt) {
            float4 b0 = *(const float4*)(wptr + (size_t)nt * 16 * 256 + k0 * 32);
            float4 b1 = *(const float4*)(wptr + (size_t)nt * 16 * 256 + k0 * 32 + 4);
            half8 b;
            b[0] = (_Float16)b0.x; b[1] = (_Float16)b0.y;
            b[2] = (_Float16)b0.z; b[3] = (_Float16)b0.w;
            b[4] = (_Float16)b1.x; b[5] = (_Float16)b1.y;
            b[6] = (_Float16)b1.z; b[7] = (_Float16)b1.w;
            acc[nt] = __builtin_amdgcn_mfma_f32_16x16x32_f16(a, b, acc[nt], 0, 0, 0);
        }
    }
}

// ---------------------------------------------------------------------------
// Merged prep+QKV, 2816 blocks, two INTERLEAVED families (bijective 3+8
// pattern per 11-block group; 768 qkv + 2048 scan = 11 x 256) so every CU
// hosts MFMA-latency waves and scan-VALU waves concurrently (pipes
// co-schedule) instead of two under-occupied sequential phases.
//   qkv family:  64x64 projection tiles (z = id>>8)
//   scan family: neighbor build, 2 waves per query (halved serial chain).
//     Wave (q, half) scans keys [half*2048, half*2048+2048) and appends to
//     sub-list nbr[q*CAP + half*HCAP + .]; count in cnt[2q+half]. List order
//     across halves is irrelevant (attention sums; CAP never reached).
// ---------------------------------------------------------------------------
__global__ __launch_bounds__(256) void prep_qkv(const float* __restrict__ cur,
                                                const float* __restrict__ histf,
                                                const float* __restrict__ Wq,
                                                const float* __restrict__ Wk,
                                                const float* __restrict__ Wv,
                                                const float* __restrict__ qc,
                                                const float* __restrict__ kc,
                                                const float* __restrict__ bq,
                                                const float* __restrict__ bk,
                                                const float* __restrict__ bv,
                                                _Float16* __restrict__ Qh,
                                                _Float16* __restrict__ KV,
                                                ushort_t* __restrict__ nbr,
                                                int* __restrict__ cnt) {
    const int b    = blockIdx.x;
    const int g    = b / 11;        // group of 11 blocks: 3 qkv + 8 scan
    const int r    = b % 11;
    const int wave = threadIdx.x >> 6;
    const int lane = threadIdx.x & 63;

    if (r < 3) {
        // ---- QKV tile; id in [0,768)
        const int id  = g * 3 + r;
        const int z   = id >> 8;        // 0:Q 1:K 2:V
        const int rem = id & 255;
        const int m0  = (rem >> 2) * 64;
        const int n0  = (rem & 3) * 64;

        const float* A    = (z == 0) ? cur : histf;
        const float* W    = (z == 0) ? Wq : (z == 1) ? Wk : Wv;
        const float* bias = (z == 0) ? bq : (z == 1) ? bk : bv;

        f32x4 acc[4];
        mfma_tile_16x64_f32AW(A, W, m0, n0, wave, lane, acc);

        const int col  = lane & 15;
        const int quad = lane >> 4;
        float bs[4];
#pragma unroll
        for (int nt = 0; nt < 4; ++nt) bs[nt] = bias[n0 + nt * 16 + col];

        if (z == 0) {
#pragma unroll
            for (int nt = 0; nt < 4; ++nt)
#pragma unroll
                for (int rr = 0; rr < 4; ++rr)
                    Qh[(size_t)(m0 + wave * 16 + quad * 4 + rr) * 256 +
                       n0 + nt * 16 + col] = (_Float16)(acc[nt][rr] + bs[nt]);
        } else {
            const int off = (z == 1) ? 0 : 256;
#pragma unroll
            for (int nt = 0; nt < 4; ++nt)
#pragma unroll
                for (int rr = 0; rr < 4; ++rr)
                    KV[(size_t)(m0 + wave * 16 + quad * 4 + rr) * 512 + off +
                       n0 + nt * 16 + col] = (_Float16)(acc[nt][rr] + bs[nt]);
        }
    } else {
        // ---- neighbor build, split-scan; idx in [0,2048)
        const int idx  = g * 8 + (r - 3);
        const int q    = idx * 2 + (wave >> 1);
        const int half = wave & 1;
        const float qx = qc[q * 3 + 0];
        const float qy = qc[q * 3 + 1];
        const float qz = qc[q * 3 + 2];
        ushort_t* dst = nbr + (size_t)q * CAP + half * HCAP;
        int base = 0;
        const int k_lo = half * 2048;
        for (int k0 = k_lo; k0 < k_lo + 2048; k0 += 64) {
            const int k = k0 + lane;
            // exact reference fp32 op order (no contraction)
            float dx = __fsub_rn(qx, kc[k * 3 + 0]);
            float dy = __fsub_rn(qy, kc[k * 3 + 1]);
            float dz = __fsub_rn(qz, kc[k * 3 + 2]);
            float d2 = __fadd_rn(__fadd_rn(__fmul_rn(dx, dx), __fmul_rn(dy, dy)),
                                 __fmul_rn(dz, dz));
            bool valid = (d2 <= R2);
            unsigned long long bal = __ballot(valid);
            if (valid) {
                int pos = base + __popcll(bal & ((1ull << lane) - 1ull));
                if (pos < HCAP) dst[pos] = (ushort_t)k;
            }
            base += __popcll(bal);
        }
        if (lane == 0) cnt[2 * q + half] = (base > HCAP) ? HCAP : base;
    }
}

// ---------------------------------------------------------------------------
// Sparse attention v12 = EXACT v9 body (measured 24us; fdot2 variant was a
// 2x regression — reverted), iterating the two scan sub-lists sequentially.
// Shift-free softmax (scores O(1)), 8 neighbor streams (wave x half-wave),
// half-wave-coalesced 1KB KV rows, f32 accumulation.
// ---------------------------------------------------------------------------
__global__ __launch_bounds__(256) void sparse_attn12(const _Float16* __restrict__ Qh,
                                                     const _Float16* __restrict__ KV,
                                                     const ushort_t* __restrict__ nbr,
                                                     const int* __restrict__ cnt,
                                                     _Float16* __restrict__ Ob) {
    __shared__ float sm[4][32][12];
    const int q    = blockIdx.x;
    const int t    = threadIdx.x;
    const int wave = t >> 6;
    const int lane = t & 63;
    const int p    = lane >> 5;
    const int h    = (lane >> 2) & 7;
    const int s    = lane & 3;
    const int koff = h * HD + s * 8;

    // 8-dim q slice for (h,s), f16 -> fp32, pre-scaled by 1/sqrt(HD)
    float qv[8];
    {
        half8 qh = *(const half8*)(Qh + (size_t)q * FDIM + koff);
        const float sc = 0.17677669529663687f;
#pragma unroll
        for (int i = 0; i < 8; ++i) qv[i] = (float)qh[i] * sc;
    }

    float o[8];
#pragma unroll
    for (int i = 0; i < 8; ++i) o[i] = 0.f;
    float l = 0.f;

    const int c0 = cnt[2 * q];
    const int c1 = cnt[2 * q + 1];
    const ushort_t* nl = nbr + (size_t)q * CAP;

#pragma unroll
    for (int sub = 0; sub < 2; ++sub) {
        const int n_s = sub ? c1 : c0;
        const ushort_t* nls = nl + sub * HCAP;
        for (int j = 2 * wave + p; j < n_s; j += 8) {
            const int k = nls[j];
            const _Float16* rr = KV + ((size_t)k << 9) + koff;
            half8 k8 = *(const half8*)(rr);
            half8 v8 = *(const half8*)(rr + 256);

            float part = 0.f;
#pragma unroll
            for (int i = 0; i < 8; ++i)
                part = fmaf(qv[i], (float)k8[i], part);
            // full 32-dim score: reduce across the 4 s-lanes of this head
            part += __shfl_xor(part, 1, 64);
            part += __shfl_xor(part, 2, 64);

            const float pw = __expf(part);
            l += pw;
#pragma unroll
            for (int i = 0; i < 8; ++i)
                o[i] = fmaf(pw, (float)v8[i], o[i]);
        }
    }

    // merge the two 32-lane halves (plain sums)
    l += __shfl_xor(l, 32, 64);
#pragma unroll
    for (int i = 0; i < 8; ++i) o[i] += __shfl_xor(o[i], 32, 64);

    if (lane < 32) {  // lane == h*4+s
        float* dst = &sm[wave][lane][0];
        *(float4*)(dst)     = (float4){o[0], o[1], o[2], o[3]};
        *(float4*)(dst + 4) = (float4){o[4], o[5], o[6], o[7]};
        dst[8] = l;
    }
    __syncthreads();

    if (t < 32) {  // t == h*4+s ; output offset = 8*t
        float4 x0 = *(const float4*)&sm[0][t][0];
        float4 x1 = *(const float4*)&sm[0][t][4];
        float O[8] = {x0.x, x0.y, x0.z, x0.w, x1.x, x1.y, x1.z, x1.w};
        float L = sm[0][t][8];
#pragma unroll
        for (int w = 1; w < 4; ++w) {
            float4 y0 = *(const float4*)&sm[w][t][0];
            float4 y1 = *(const float4*)&sm[w][t][4];
            L += sm[w][t][8];
            O[0] += y0.x; O[1] += y0.y; O[2] += y0.z; O[3] += y0.w;
            O[4] += y1.x; O[5] += y1.y; O[6] += y1.z; O[7] += y1.w;
        }
        const float inv = 1.0f / L;  // n==0 -> L==0 -> inf -> NaN, matches ref
        half8 ho;
#pragma unroll
        for (int i = 0; i < 8; ++i) ho[i] = (_Float16)(O[i] * inv);
        *(half8*)(Ob + (size_t)q * FDIM + t * 8) = ho;
    }
}

// O-projection: out fp32 = Ob_f16 * (f16)Wo^T + bo  (Wo converted in-register)
__global__ __launch_bounds__(256) void o_mfma(const _Float16* __restrict__ Ob,
                                              const float* __restrict__ Wo,
                                              const float* __restrict__ bo,
                                              float* __restrict__ out) {
    const int wave = threadIdx.x >> 6;
    const int lane = threadIdx.x & 63;
    const int m0   = blockIdx.y * 64;
    const int n0   = blockIdx.x * 64;

    f32x4 acc[4];
    mfma_tile_16x64_f16A_f32W(Ob, Wo, m0, n0, wave, lane, acc);

    const int col  = lane & 15;
    const int quad = lane >> 4;
#pragma unroll
    for (int nt = 0; nt < 4; ++nt) {
        const float b = bo[n0 + nt * 16 + col];
#pragma unroll
        for (int r = 0; r < 4; ++r)
            out[(size_t)(m0 + wave * 16 + quad * 4 + r) * 256 + n0 + nt * 16 + col] =
                acc[nt][r] + b;
    }
}

// ---------------------------------------------------------------------------
extern "C" void kernel_launch(void* const* d_in, const int* in_sizes, int n_in,
                              void* d_out, int out_size, void* d_ws, size_t ws_size,
                              hipStream_t stream) {
    const float* cur_feats   = (const float*)d_in[0];
    const float* hist_feats  = (const float*)d_in[1];
    const float* cur_coords  = (const float*)d_in[2];
    const float* hist_coords = (const float*)d_in[3];
    const float* Wq = (const float*)d_in[4];
    const float* bq = (const float*)d_in[5];
    const float* Wk = (const float*)d_in[6];
    const float* bk = (const float*)d_in[7];
    const float* Wv = (const float*)d_in[8];
    const float* bv = (const float*)d_in[9];
    const float* Wo = (const float*)d_in[10];
    const float* bo = (const float*)d_in[11];
    float* out = (float*)d_out;

    char* w = (char*)d_ws;
    _Float16*  Qh  = (_Float16*)(w);                           // 2 MiB
    _Float16*  KV  = (_Float16*)(w + (4 << 20));               // 4 MiB
    ushort_t*  nbr = (ushort_t*)(w + (8 << 20));               // 4 MiB
    int*       cnt = (int*)(w + (12 << 20));                   // 32 KiB (2 per q)
    _Float16*  Ob  = (_Float16*)(w + (12 << 20) + (64 << 10)); // 2 MiB

    prep_qkv<<<2816, 256, 0, stream>>>(cur_feats, hist_feats, Wq, Wk, Wv,
                                       cur_coords, hist_coords, bq, bk, bv,
                                       Qh, KV, nbr, cnt);

    sparse_attn12<<<NQ, 256, 0, stream>>>(Qh, KV, nbr, cnt, Ob);

    o_mfma<<<dim3(4, 64), 256, 0, stream>>>(Ob, Wo, bo, out);
}

// Round 7
// 149.221 us; speedup vs baseline: 1.1346x; 1.1346x over previous
//
#include <hip/hip_runtime.h>
#include <math.h>

#define FDIM 256
#define NH 8
#define HD 32
#define NQ 4096
#define NKEY 4096
#define CAP 512
#define R2 9.0f

typedef _Float16 half8 __attribute__((ext_vector_type(8)));
typedef float f32x4 __attribute__((ext_vector_type(4)));
typedef unsigned short ushort_t;

// ---------------------------------------------------------------------------
// MFMA GEMM cores: C[m][n] = sum_k A[m][k] * W[n][k]  (K=256). Wave tile
// 16x64, no LDS. f32 operands are converted in-register (single RN rounding,
// numerically identical to a separate cast pass).
// ---------------------------------------------------------------------------
__device__ __forceinline__ void mfma_tile_16x64_f32AW(const float* __restrict__ A,
                                                      const float* __restrict__ W,
                                                      int m0, int n0, int wave, int lane,
                                                      f32x4 acc[4]) {
    const int row  = lane & 15;
    const int quad = lane >> 4;
    const float* aptr = A + (size_t)(m0 + wave * 16 + row) * 256 + quad * 8;
    const float* wptr = W + (size_t)(n0 + row) * 256 + quad * 8;
#pragma unroll
    for (int i = 0; i < 4; ++i) acc[i] = (f32x4){0.f, 0.f, 0.f, 0.f};
#pragma unroll
    for (int k0 = 0; k0 < 8; ++k0) {
        float4 a0 = *(const float4*)(aptr + k0 * 32);
        float4 a1 = *(const float4*)(aptr + k0 * 32 + 4);
        half8 a;
        a[0] = (_Float16)a0.x; a[1] = (_Float16)a0.y;
        a[2] = (_Float16)a0.z; a[3] = (_Float16)a0.w;
        a[4] = (_Float16)a1.x; a[5] = (_Float16)a1.y;
        a[6] = (_Float16)a1.z; a[7] = (_Float16)a1.w;
#pragma unroll
        for (int nt = 0; nt < 4; ++nt) {
            float4 b0 = *(const float4*)(wptr + (size_t)nt * 16 * 256 + k0 * 32);
            float4 b1 = *(const float4*)(wptr + (size_t)nt * 16 * 256 + k0 * 32 + 4);
            half8 b;
            b[0] = (_Float16)b0.x; b[1] = (_Float16)b0.y;
            b[2] = (_Float16)b0.z; b[3] = (_Float16)b0.w;
            b[4] = (_Float16)b1.x; b[5] = (_Float16)b1.y;
            b[6] = (_Float16)b1.z; b[7] = (_Float16)b1.w;
            acc[nt] = __builtin_amdgcn_mfma_f32_16x16x32_f16(a, b, acc[nt], 0, 0, 0);
        }
    }
}

__device__ __forceinline__ void mfma_tile_16x64_f16A_f32W(const _Float16* __restrict__ A,
                                                          const float* __restrict__ W,
                                                          int m0, int n0, int wave, int lane,
                                                          f32x4 acc[4]) {
    const int row  = lane & 15;
    const int quad = lane >> 4;
    const _Float16* aptr = A + (size_t)(m0 + wave * 16 + row) * 256 + quad * 8;
    const float* wptr = W + (size_t)(n0 + row) * 256 + quad * 8;
#pragma unroll
    for (int i = 0; i < 4; ++i) acc[i] = (f32x4){0.f, 0.f, 0.f, 0.f};
#pragma unroll
    for (int k0 = 0; k0 < 8; ++k0) {
        half8 a = *(const half8*)(aptr + k0 * 32);
#pragma unroll
        for (int nt = 0; nt < 4; ++nt) {
            float4 b0 = *(const float4*)(wptr + (size_t)nt * 16 * 256 + k0 * 32);
            float4 b1 = *(const float4*)(wptr + (size_t)nt * 16 * 256 + k0 * 32 + 4);
            half8 b;
            b[0] = (_Float16)b0.x; b[1] = (_Float16)b0.y;
            b[2] = (_Float16)b0.z; b[3] = (_Float16)b0.w;
            b[4] = (_Float16)b1.x; b[5] = (_Float16)b1.y;
            b[6] = (_Float16)b1.z; b[7] = (_Float16)b1.w;
            acc[nt] = __builtin_amdgcn_mfma_f32_16x16x32_f16(a, b, acc[nt], 0, 0, 0);
        }
    }
}

// ---------------------------------------------------------------------------
// Merged prep+QKV, round-5 block layout (measured 53us; round-6 interleave
// regressed by thrashing the scan's kc L2 set with the GEMM stream):
//   blocks [0,768):    QKV projection tiles (z = id>>8; 64x64 tile each)
//   blocks [768,1792): neighbor build, 4 queries/block, kc LDS-STAGED.
// Scan fix: the 4 waves of a scan block all stream the same 48KB of key
// coords -> stage kc in 4 x 12KB LDS chunks (coalesced float4 loads), scan
// from LDS (2-way bank aliasing, free). Cuts global coord traffic 4x and
// removes the ~200cy L2 load from the per-iteration critical path. Key
// order / fp32 op order / compaction identical -> bit-same nbr, cnt.
// ---------------------------------------------------------------------------
__global__ __launch_bounds__(256) void prep_qkv(const float* __restrict__ cur,
                                                const float* __restrict__ histf,
                                                const float* __restrict__ Wq,
                                                const float* __restrict__ Wk,
                                                const float* __restrict__ Wv,
                                                const float* __restrict__ qc,
                                                const float* __restrict__ kc,
                                                const float* __restrict__ bq,
                                                const float* __restrict__ bk,
                                                const float* __restrict__ bv,
                                                _Float16* __restrict__ Qh,
                                                _Float16* __restrict__ KV,
                                                ushort_t* __restrict__ nbr,
                                                int* __restrict__ cnt) {
    __shared__ float ldsc[3072];  // 1024 keys x 3 coords (12 KB)
    const int b    = blockIdx.x;
    const int t    = threadIdx.x;
    const int wave = t >> 6;
    const int lane = t & 63;

    if (b < 768) {
        // ---- QKV tile
        const int z   = b >> 8;        // 0:Q 1:K 2:V
        const int rem = b & 255;
        const int m0  = (rem >> 2) * 64;
        const int n0  = (rem & 3) * 64;

        const float* A    = (z == 0) ? cur : histf;
        const float* W    = (z == 0) ? Wq : (z == 1) ? Wk : Wv;
        const float* bias = (z == 0) ? bq : (z == 1) ? bk : bv;

        f32x4 acc[4];
        mfma_tile_16x64_f32AW(A, W, m0, n0, wave, lane, acc);

        const int col  = lane & 15;
        const int quad = lane >> 4;
        float bs[4];
#pragma unroll
        for (int nt = 0; nt < 4; ++nt) bs[nt] = bias[n0 + nt * 16 + col];

        if (z == 0) {
#pragma unroll
            for (int nt = 0; nt < 4; ++nt)
#pragma unroll
                for (int rr = 0; rr < 4; ++rr)
                    Qh[(size_t)(m0 + wave * 16 + quad * 4 + rr) * 256 +
                       n0 + nt * 16 + col] = (_Float16)(acc[nt][rr] + bs[nt]);
        } else {
            const int off = (z == 1) ? 0 : 256;
#pragma unroll
            for (int nt = 0; nt < 4; ++nt)
#pragma unroll
                for (int rr = 0; rr < 4; ++rr)
                    KV[(size_t)(m0 + wave * 16 + quad * 4 + rr) * 512 + off +
                       n0 + nt * 16 + col] = (_Float16)(acc[nt][rr] + bs[nt]);
        }
    } else {
        // ---- neighbor build, kc LDS-staged; 1 query per wave
        const int q  = (b - 768) * 4 + wave;
        const float qx = qc[q * 3 + 0];
        const float qy = qc[q * 3 + 1];
        const float qz = qc[q * 3 + 2];
        ushort_t* dst = nbr + (size_t)q * CAP;
        int base = 0;
#pragma unroll 1
        for (int c = 0; c < 4; ++c) {
            __syncthreads();  // prior chunk fully consumed before overwrite
            // cooperative stage: 768 float4s, 3 per thread, coalesced
#pragma unroll
            for (int i = 0; i < 3; ++i) {
                const int idx = t + 256 * i;
                ((float4*)ldsc)[idx] = ((const float4*)kc)[c * 768 + idx];
            }
            __syncthreads();
            for (int k0 = 0; k0 < 1024; k0 += 64) {
                const int kk = k0 + lane;
                // exact reference fp32 op order (no contraction)
                float dx = __fsub_rn(qx, ldsc[kk * 3 + 0]);
                float dy = __fsub_rn(qy, ldsc[kk * 3 + 1]);
                float dz = __fsub_rn(qz, ldsc[kk * 3 + 2]);
                float d2 = __fadd_rn(__fadd_rn(__fmul_rn(dx, dx), __fmul_rn(dy, dy)),
                                     __fmul_rn(dz, dz));
                bool valid = (d2 <= R2);
                unsigned long long bal = __ballot(valid);
                if (valid) {
                    int pos = base + __popcll(bal & ((1ull << lane) - 1ull));
                    if (pos < CAP) dst[pos] = (ushort_t)(c * 1024 + kk);
                }
                base += __popcll(bal);
            }
        }
        if (lane == 0) cnt[q] = (base > CAP) ? CAP : base;
    }
}

// ---------------------------------------------------------------------------
// Sparse attention v9 (exact body; measured 24us in round 4): shift-free
// softmax (scores O(1), q,k ~ N(0,1)), 8 neighbor streams (wave x
// half-wave), half-wave-coalesced 1KB KV rows, f32 accumulation.
// ---------------------------------------------------------------------------
__global__ __launch_bounds__(256) void sparse_attn9(const _Float16* __restrict__ Qh,
                                                    const _Float16* __restrict__ KV,
                                                    const ushort_t* __restrict__ nbr,
                                                    const int* __restrict__ cnt,
                                                    _Float16* __restrict__ Ob) {
    __shared__ float sm[4][32][12];
    const int q    = blockIdx.x;
    const int t    = threadIdx.x;
    const int wave = t >> 6;
    const int lane = t & 63;
    const int p    = lane >> 5;
    const int h    = (lane >> 2) & 7;
    const int s    = lane & 3;
    const int koff = h * HD + s * 8;

    // 8-dim q slice for (h,s), f16 -> fp32, pre-scaled by 1/sqrt(HD)
    float qv[8];
    {
        half8 qh = *(const half8*)(Qh + (size_t)q * FDIM + koff);
        const float sc = 0.17677669529663687f;
#pragma unroll
        for (int i = 0; i < 8; ++i) qv[i] = (float)qh[i] * sc;
    }

    float o[8];
#pragma unroll
    for (int i = 0; i < 8; ++i) o[i] = 0.f;
    float l = 0.f;

    const int n = cnt[q];
    const ushort_t* nl = nbr + (size_t)q * CAP;

    for (int j = 2 * wave + p; j < n; j += 8) {
        const int k = nl[j];
        const _Float16* r = KV + ((size_t)k << 9) + koff;
        half8 k8 = *(const half8*)(r);
        half8 v8 = *(const half8*)(r + 256);

        float part = 0.f;
#pragma unroll
        for (int i = 0; i < 8; ++i)
            part = fmaf(qv[i], (float)k8[i], part);
        // full 32-dim score: reduce across the 4 s-lanes of this head
        part += __shfl_xor(part, 1, 64);
        part += __shfl_xor(part, 2, 64);

        const float pw = __expf(part);
        l += pw;
#pragma unroll
        for (int i = 0; i < 8; ++i)
            o[i] = fmaf(pw, (float)v8[i], o[i]);
    }

    // merge the two 32-lane halves (plain sums)
    l += __shfl_xor(l, 32, 64);
#pragma unroll
    for (int i = 0; i < 8; ++i) o[i] += __shfl_xor(o[i], 32, 64);

    if (lane < 32) {  // lane == h*4+s
        float* dst = &sm[wave][lane][0];
        *(float4*)(dst)     = (float4){o[0], o[1], o[2], o[3]};
        *(float4*)(dst + 4) = (float4){o[4], o[5], o[6], o[7]};
        dst[8] = l;
    }
    __syncthreads();

    if (t < 32) {  // t == h*4+s ; output offset = 8*t
        float4 x0 = *(const float4*)&sm[0][t][0];
        float4 x1 = *(const float4*)&sm[0][t][4];
        float O[8] = {x0.x, x0.y, x0.z, x0.w, x1.x, x1.y, x1.z, x1.w};
        float L = sm[0][t][8];
#pragma unroll
        for (int w = 1; w < 4; ++w) {
            float4 y0 = *(const float4*)&sm[w][t][0];
            float4 y1 = *(const float4*)&sm[w][t][4];
            L += sm[w][t][8];
            O[0] += y0.x; O[1] += y0.y; O[2] += y0.z; O[3] += y0.w;
            O[4] += y1.x; O[5] += y1.y; O[6] += y1.z; O[7] += y1.w;
        }
        const float inv = 1.0f / L;  // n==0 -> L==0 -> inf -> NaN, matches ref
        half8 ho;
#pragma unroll
        for (int i = 0; i < 8; ++i) ho[i] = (_Float16)(O[i] * inv);
        *(half8*)(Ob + (size_t)q * FDIM + t * 8) = ho;
    }
}

// O-projection: out fp32 = Ob_f16 * (f16)Wo^T + bo  (Wo converted in-register)
__global__ __launch_bounds__(256) void o_mfma(const _Float16* __restrict__ Ob,
                                              const float* __restrict__ Wo,
                                              const float* __restrict__ bo,
                                              float* __restrict__ out) {
    const int wave = threadIdx.x >> 6;
    const int lane = threadIdx.x & 63;
    const int m0   = blockIdx.y * 64;
    const int n0   = blockIdx.x * 64;

    f32x4 acc[4];
    mfma_tile_16x64_f16A_f32W(Ob, Wo, m0, n0, wave, lane, acc);

    const int col  = lane & 15;
    const int quad = lane >> 4;
#pragma unroll
    for (int nt = 0; nt < 4; ++nt) {
        const float b = bo[n0 + nt * 16 + col];
#pragma unroll
        for (int r = 0; r < 4; ++r)
            out[(size_t)(m0 + wave * 16 + quad * 4 + r) * 256 + n0 + nt * 16 + col] =
                acc[nt][r] + b;
    }
}

// ---------------------------------------------------------------------------
extern "C" void kernel_launch(void* const* d_in, const int* in_sizes, int n_in,
                              void* d_out, int out_size, void* d_ws, size_t ws_size,
                              hipStream_t stream) {
    const float* cur_feats   = (const float*)d_in[0];
    const float* hist_feats  = (const float*)d_in[1];
    const float* cur_coords  = (const float*)d_in[2];
    const float* hist_coords = (const float*)d_in[3];
    const float* Wq = (const float*)d_in[4];
    const float* bq = (const float*)d_in[5];
    const float* Wk = (const float*)d_in[6];
    const float* bk = (const float*)d_in[7];
    const float* Wv = (const float*)d_in[8];
    const float* bv = (const float*)d_in[9];
    const float* Wo = (const float*)d_in[10];
    const float* bo = (const float*)d_in[11];
    float* out = (float*)d_out;

    char* w = (char*)d_ws;
    _Float16*  Qh  = (_Float16*)(w);                           // 2 MiB
    _Float16*  KV  = (_Float16*)(w + (4 << 20));               // 4 MiB
    ushort_t*  nbr = (ushort_t*)(w + (8 << 20));               // 4 MiB
    int*       cnt = (int*)(w + (12 << 20));                   // 16 KiB
    _Float16*  Ob  = (_Float16*)(w + (12 << 20) + (64 << 10)); // 2 MiB

    prep_qkv<<<1792, 256, 0, stream>>>(cur_feats, hist_feats, Wq, Wk, Wv,
                                       cur_coords, hist_coords, bq, bk, bv,
                                       Qh, KV, nbr, cnt);

    sparse_attn9<<<NQ, 256, 0, stream>>>(Qh, KV, nbr, cnt, Ob);

    o_mfma<<<dim3(4, 64), 256, 0, stream>>>(Ob, Wo, bo, out);
}